// Round 8
// baseline (140.893 us; speedup 1.0000x reference)
//
#include <hip/hip_runtime.h>
#include <hip/hip_bf16.h>

#define NB 32
#define DIN 512
#define TT 4096
#define DH 500
#define DHP 512
#define EPSV 1e-12f
#define BM 64
#define LDA 520            // bf16 elems; 1040B row stride, 16B-aligned rows
#define NTILES (TT / BM)   // 64 t-tiles per batch

typedef short short8 __attribute__((ext_vector_type(8)));
typedef float f32x16 __attribute__((ext_vector_type(16)));
typedef float f32x4 __attribute__((ext_vector_type(4)));
typedef unsigned int u32x4 __attribute__((ext_vector_type(4)));

__device__ inline unsigned short f2bf(float f) {
    unsigned int u = __builtin_bit_cast(unsigned int, f);
    unsigned int r = (u + 0x7fffu + ((u >> 16) & 1u)) >> 16;
    return (unsigned short)r;
}
__device__ inline float bf2f(unsigned short h) {
    unsigned int u = ((unsigned int)h) << 16;
    return __builtin_bit_cast(float, u);
}

// Kernel 0: pack w1 -> bf16 MFMA-fragment order [hb=16][ks=32][lane=64][8]
//   h = hb*32 + (lane&31),  d = ks*16 + (lane>>5)*8 + j
__global__ void prep_kernel(const float* __restrict__ w1, const float* __restrict__ w2,
                            unsigned short* __restrict__ w1b, float* __restrict__ w2f) {
    int idx = blockIdx.x * blockDim.x + threadIdx.x;
    if (idx < DHP * DIN) {
        const int j    = idx & 7;
        const int lane = (idx >> 3) & 63;
        const int ks   = (idx >> 9) & 31;
        const int hb   = idx >> 14;
        const int h = hb * 32 + (lane & 31);
        const int d = ks * 16 + (lane >> 5) * 8 + j;
        float v = (h < DH) ? w1[h * DIN + d] : 0.f;
        w1b[idx] = f2bf(v);
        if (idx < DHP) w2f[idx] = (idx < DH) ? w2[idx] : 0.f;
    }
}

// Kernel 1 (fused): per (b, 64-t tile): scores -> block softmax partial ->
// per-d partials (sx, sx2, swx). Stage: float4 global loads (8 KB/wave in
// flight), per-t register repack via v_cvt_pk_bf16_f32, b128 LDS row writes.
__launch_bounds__(512, 4)
__global__ void scores_fused(const float* __restrict__ x,
                             const unsigned short* __restrict__ w1b,
                             const float* __restrict__ w2f,
                             float* __restrict__ pm, float* __restrict__ pz,
                             float* __restrict__ pswx, float* __restrict__ psx,
                             float* __restrict__ psx2) {
    __shared__ unsigned short A_lds[BM][LDA];
    __shared__ float score_p[8][BM];
    __shared__ float w_lds[BM];

    const int tid = threadIdx.x;
    const int b = blockIdx.x >> 6;             // NTILES = 64 tiles per batch
    const int t0 = (blockIdx.x & 63) * BM;

    // ---- Phase 1: stage x[b, :, t0..t0+63] -> A_lds[t][d] (bf16) ----
    // thread: q = tid&15 (t = 4q..4q+3), r = tid>>4 (d = 16r..16r+15).
    // Per half: 8 float4 loads (d-octet x 4t), repack per-t, 4 b128 writes.
    {
        const int q = tid & 15;
        const int r = tid >> 4;
        const float* xb = x + (size_t)b * DIN * TT + t0 + 4 * q;
        #pragma unroll
        for (int half = 0; half < 2; ++half) {
            const int d0 = r * 16 + half * 8;
            f32x4 v[8];
            #pragma unroll
            for (int j = 0; j < 8; ++j)
                v[j] = *reinterpret_cast<const f32x4*>(xb + (size_t)(d0 + j) * TT);
            #pragma unroll
            for (int i = 0; i < 4; ++i) {
                unsigned int p0, p1, p2, p3;
                asm("v_cvt_pk_bf16_f32 %0, %1, %2" : "=v"(p0) : "v"(v[0][i]), "v"(v[1][i]));
                asm("v_cvt_pk_bf16_f32 %0, %1, %2" : "=v"(p1) : "v"(v[2][i]), "v"(v[3][i]));
                asm("v_cvt_pk_bf16_f32 %0, %1, %2" : "=v"(p2) : "v"(v[4][i]), "v"(v[5][i]));
                asm("v_cvt_pk_bf16_f32 %0, %1, %2" : "=v"(p3) : "v"(v[6][i]), "v"(v[7][i]));
                u32x4 pk; pk[0] = p0; pk[1] = p1; pk[2] = p2; pk[3] = p3;
                *reinterpret_cast<u32x4*>(&A_lds[4 * q + i][d0]) = pk;
            }
        }
    }
    __syncthreads();

    // ---- Phase 2: MFMA. Wave w owns h-panels {2w,2w+1}; A=w1 (m=h),
    // B=x^T (n=t): D cols (lane&31)=t, rows=h -> relu*w2 reduce in-lane.
    const int w = tid >> 6;
    const int lane = tid & 63;
    const int lane31 = lane & 31;
    const int khalf = lane >> 5;
    const int hrow0 = w * 64;

    float w20v[16], w21v[16];
    #pragma unroll
    for (int g = 0; g < 16; ++g) {
        const int rp = (g & 3) + 8 * (g >> 2) + 4 * khalf;
        w20v[g] = w2f[hrow0 + rp];
        w21v[g] = w2f[hrow0 + 32 + rp];
    }

    f32x16 acc00, acc01, acc10, acc11;
    #pragma unroll
    for (int g = 0; g < 16; ++g) { acc00[g] = 0.f; acc01[g] = 0.f; acc10[g] = 0.f; acc11[g] = 0.f; }

    const unsigned short* base0 = w1b + (size_t)w * 32768 + (size_t)lane * 8;
    const unsigned short* base1 = base0 + 16384;
    const unsigned short* Bp0 = &A_lds[lane31][khalf * 8];
    const unsigned short* Bp1 = &A_lds[32 + lane31][khalf * 8];

    #pragma unroll 4
    for (int ks = 0; ks < 32; ++ks) {
        short8 a0 = *reinterpret_cast<const short8*>(base0 + ks * 512);
        short8 a1 = *reinterpret_cast<const short8*>(base1 + ks * 512);
        short8 b0 = *reinterpret_cast<const short8*>(Bp0 + ks * 16);
        short8 b1 = *reinterpret_cast<const short8*>(Bp1 + ks * 16);
        acc00 = __builtin_amdgcn_mfma_f32_32x32x16_bf16(a0, b0, acc00, 0, 0, 0);
        acc01 = __builtin_amdgcn_mfma_f32_32x32x16_bf16(a0, b1, acc01, 0, 0, 0);
        acc10 = __builtin_amdgcn_mfma_f32_32x32x16_bf16(a1, b0, acc10, 0, 0, 0);
        acc11 = __builtin_amdgcn_mfma_f32_32x32x16_bf16(a1, b1, acc11, 0, 0, 0);
    }

    float s0 = 0.f, s1 = 0.f;
    #pragma unroll
    for (int g = 0; g < 16; ++g) {
        s0 += fmaxf(acc00[g], 0.f) * w20v[g] + fmaxf(acc10[g], 0.f) * w21v[g];
        s1 += fmaxf(acc01[g], 0.f) * w20v[g] + fmaxf(acc11[g], 0.f) * w21v[g];
    }
    s0 += __shfl_xor(s0, 32, 64);
    s1 += __shfl_xor(s1, 32, 64);
    if (khalf == 0) {                          // deterministic per-wave partials
        score_p[w][lane31] = s0;
        score_p[w][32 + lane31] = s1;
    }
    __syncthreads();

    // ---- Phase 3: wave 0 finalizes scores -> e_t, m_blk, Z_blk ----
    if (tid < BM) {
        float s = 0.f;
        #pragma unroll
        for (int ww = 0; ww < 8; ++ww) s += score_p[ww][tid];
        float m = s;
        #pragma unroll
        for (int k = 1; k <= 32; k <<= 1) m = fmaxf(m, __shfl_xor(m, k, 64));
        float e = __expf(s - m);
        float Z = e;
        #pragma unroll
        for (int k = 1; k <= 32; k <<= 1) Z += __shfl_xor(Z, k, 64);
        w_lds[tid] = e;
        if (tid == 0) { pm[blockIdx.x] = m; pz[blockIdx.x] = Z; }
    }
    __syncthreads();

    // ---- Phase 4: per-d partials over the tile's 64 t ----
    {
        const int d = tid;                     // 0..511
        float sx = 0.f, sx2 = 0.f, swx = 0.f;
        #pragma unroll 8
        for (int t = 0; t < BM; ++t) {
            const float xv = bf2f(A_lds[t][d]);
            const float wv = w_lds[t];
            sx += xv; sx2 += xv * xv; swx += wv * xv;
        }
        const size_t o = (size_t)blockIdx.x * DHP + d;
        psx[o] = sx; psx2[o] = sx2; pswx[o] = swx;
    }
}

// Kernel 2: combine 64 tiles per batch -> mean, stddev
__global__ void combine_kernel(const float* __restrict__ pm, const float* __restrict__ pz,
                               const float* __restrict__ pswx, const float* __restrict__ psx,
                               const float* __restrict__ psx2, float* __restrict__ out) {
    __shared__ float sm[NTILES], sz[NTILES];
    const int b = blockIdx.x;
    const int tid = threadIdx.x;               // d = tid, 0..511
    if (tid < NTILES) { sm[tid] = pm[b * NTILES + tid]; sz[tid] = pz[b * NTILES + tid]; }
    __syncthreads();

    float mg = -1e30f;
    #pragma unroll 8
    for (int i = 0; i < NTILES; ++i) mg = fmaxf(mg, sm[i]);
    float denom = 0.f;
    #pragma unroll 8
    for (int i = 0; i < NTILES; ++i) denom += sz[i] * __expf(sm[i] - mg);

    float num = 0.f, sx = 0.f, sx2 = 0.f;
    #pragma unroll 4
    for (int i = 0; i < NTILES; ++i) {
        const size_t o = ((size_t)(b * NTILES + i)) * DHP + tid;
        const float f = __expf(sm[i] - mg);
        num += f * pswx[o];
        sx  += psx[o];
        sx2 += psx2[o];
    }
    const float mean = num / denom;
    const float ex  = sx  * (1.f / TT);
    const float ex2 = sx2 * (1.f / TT);
    float var = ex2 - 2.f * mean * ex + mean * mean;
    if (var <= EPSV) var = EPSV;
    out[(size_t)b * 1024 + tid] = mean;
    out[(size_t)b * 1024 + 512 + tid] = sqrtf(var);
}

extern "C" void kernel_launch(void* const* d_in, const int* in_sizes, int n_in,
                              void* d_out, int out_size, void* d_ws, size_t ws_size,
                              hipStream_t stream) {
    const float* x  = (const float*)d_in[0];
    const float* w1 = (const float*)d_in[1];
    const float* w2 = (const float*)d_in[2];
    float* out = (float*)d_out;

    char* ws = (char*)d_ws;
    unsigned short* w1b = (unsigned short*)ws;                    // 512 KB
    float* w2f  = (float*)(ws + 524288);                          // 2 KB
    float* pm   = (float*)(ws + 526336);                          // 8 KB
    float* pz   = (float*)(ws + 534528);                          // 8 KB
    float* pswx = (float*)(ws + 542720);                          // 4 MB
    float* psx  = pswx + (size_t)NB * NTILES * DHP;               // 4 MB
    float* psx2 = psx  + (size_t)NB * NTILES * DHP;               // 4 MB

    prep_kernel<<<(DHP * DIN + 255) / 256, 256, 0, stream>>>(w1, w2, w1b, w2f);
    scores_fused<<<NB * NTILES, 512, 0, stream>>>(x, w1b, w2f, pm, pz, pswx, psx, psx2);
    combine_kernel<<<NB, 512, 0, stream>>>(pm, pz, pswx, psx, psx2, out);
}